// Round 1
// baseline (17586.530 us; speedup 1.0000x reference)
//
#include <hip/hip_runtime.h>
#include <hip/hip_cooperative_groups.h>

namespace cg = cooperative_groups;

typedef __attribute__((ext_vector_type(8))) short short8;
typedef __attribute__((ext_vector_type(4))) float f32x4;

#define NBATCH 256
#define NSTEP  128
#define NFEAT  128
#define NHID   1024
#define NGATE  4096
#define KA     1152
#define KB     2048
#define NOUT   128
#define KOUT   131072

__device__ __forceinline__ unsigned short f2bf(float f){
  unsigned u = __float_as_uint(f);
  u += 0x7fffu + ((u >> 16) & 1u);
  return (unsigned short)(u >> 16);
}
__device__ __forceinline__ float sigf(float x){
  x = fminf(fmaxf(x, -30.f), 30.f);
  return 1.f / (1.f + __expf(-x));
}
__device__ __forceinline__ float tanhf_(float x){
  x = fminf(fmaxf(x, -15.f), 15.f);
  float e = __expf(2.f * x);
  return (e - 1.f) / (e + 1.f);
}

struct Params {
  const float *batch,*Wih0,*Whh0,*bih0,*bhh0,*Wih1,*Whh1,*bih1,*bhh1,*h00,*c00,*h01,*c01,*Wout,*bout;
  float *out;
  unsigned short *W0,*W1,*h0b,*h1b,*outs;
  float *b0f,*b1f,*partial;
};

__device__ __forceinline__ short8 ld8(const unsigned short* p){
  return *(const short8*)p;
}
__device__ __forceinline__ short8 ld8f(const float* p){
  f32x4 a = *(const f32x4*)p;
  f32x4 b = *(const f32x4*)(p + 4);
  short8 r;
  r[0]=(short)f2bf(a[0]); r[1]=(short)f2bf(a[1]); r[2]=(short)f2bf(a[2]); r[3]=(short)f2bf(a[3]);
  r[4]=(short)f2bf(b[0]); r[5]=(short)f2bf(b[1]); r[6]=(short)f2bf(b[2]); r[7]=(short)f2bf(b[3]);
  return r;
}

// One recurrent GEMM phase for one block + fused LSTM-cell epilogue.
// Computes D[n][m] = sum_k W[n][k] * act[m][k]   (gates transposed)
// wave w handles n-fragment nf = w exclusively; all 8 m-fragments.
__device__ __forceinline__ void gemm_layer(const Params& a, bool g0, int t, int rp, int wpar,
                                           int mt, int nt, int w, int lo, int hi, float (&creg)[8])
{
  const int m0 = mt * 128, n0 = nt * 64;
  f32x4 acc[8];
  #pragma unroll
  for (int i = 0; i < 8; i++) acc[i] = (f32x4)(0.f);

  if (g0) {
    const unsigned short* wrow = a.W0 + (size_t)(n0 + w*16 + lo) * KA + hi*8;
    // segment 1: x_t from batch (fp32, row stride NFEAT), k = 0..127
    const float* xp = a.batch + (size_t)t * NBATCH * NFEAT + (size_t)(m0 + lo) * NFEAT + hi*8;
    #pragma unroll
    for (int kc = 0; kc < 4; kc++) {
      short8 wf = ld8(wrow + kc*32);
      #pragma unroll
      for (int mf = 0; mf < 8; mf++) {
        short8 af = ld8f(xp + mf*16*NFEAT + kc*32);
        acc[mf] = __builtin_amdgcn_mfma_f32_16x16x32_bf16(wf, af, acc[mf], 0, 0, 0);
      }
    }
    // segment 2: h0_prev (bf16, row stride NHID), k = 128..1151
    const unsigned short* hp = a.h0b + (size_t)rp * NBATCH * NHID + (size_t)(m0 + lo) * NHID + hi*8;
    const unsigned short* wp2 = wrow + NFEAT;
    #pragma unroll 2
    for (int kc = 0; kc < 32; kc++) {
      short8 wf = ld8(wp2 + kc*32);
      #pragma unroll
      for (int mf = 0; mf < 8; mf++) {
        short8 af = ld8(hp + mf*16*NHID + kc*32);
        acc[mf] = __builtin_amdgcn_mfma_f32_16x16x32_bf16(wf, af, acc[mf], 0, 0, 0);
      }
    }
  } else {
    const unsigned short* wrow = a.W1 + (size_t)(n0 + w*16 + lo) * KB + hi*8;
    // segment 1: h0 (this step's layer0 output from previous phase), k = 0..1023
    const unsigned short* hp0 = a.h0b + (size_t)rp * NBATCH * NHID + (size_t)(m0 + lo) * NHID + hi*8;
    #pragma unroll 2
    for (int kc = 0; kc < 32; kc++) {
      short8 wf = ld8(wrow + kc*32);
      #pragma unroll
      for (int mf = 0; mf < 8; mf++) {
        short8 af = ld8(hp0 + mf*16*NHID + kc*32);
        acc[mf] = __builtin_amdgcn_mfma_f32_16x16x32_bf16(wf, af, acc[mf], 0, 0, 0);
      }
    }
    // segment 2: h1_prev, k = 1024..2047
    const unsigned short* hp1 = a.h1b + (size_t)wpar * NBATCH * NHID + (size_t)(m0 + lo) * NHID + hi*8;
    const unsigned short* wp2 = wrow + NHID;
    #pragma unroll 2
    for (int kc = 0; kc < 32; kc++) {
      short8 wf = ld8(wp2 + kc*32);
      #pragma unroll
      for (int mf = 0; mf < 8; mf++) {
        short8 af = ld8(hp1 + mf*16*NHID + kc*32);
        acc[mf] = __builtin_amdgcn_mfma_f32_16x16x32_bf16(wf, af, acc[mf], 0, 0, 0);
      }
    }
  }

  // epilogue: lane holds (i,f,g,o) for unit jq, batch rows m0+mf*16+lo
  const int jq = nt*16 + w*4 + hi;
  const float* bias = g0 ? a.b0f : a.b1f;
  f32x4 bq = *(const f32x4*)(bias + 4*jq);
  unsigned short* hout = g0 ? (a.h0b + (size_t)wpar * NBATCH * NHID)
                            : (a.h1b + (size_t)rp   * NBATCH * NHID);
  #pragma unroll
  for (int mf = 0; mf < 8; mf++) {
    int m = m0 + mf*16 + lo;
    float gi = acc[mf][0] + bq[0];
    float gf = acc[mf][1] + bq[1];
    float gg = acc[mf][2] + bq[2];
    float go = acc[mf][3] + bq[3];
    float cn = sigf(gf) * creg[mf] + sigf(gi) * tanhf_(gg);
    creg[mf] = cn;
    unsigned short hb = f2bf(sigf(go) * tanhf_(cn));
    hout[(size_t)m * NHID + jq] = hb;
    if (!g0) a.outs[(size_t)t * NBATCH * NHID + (size_t)m * NHID + jq] = hb;
  }
}

__global__ void __launch_bounds__(256) lstm_all(Params a)
{
  const int bx = blockIdx.x, tid = threadIdx.x;
  const int gtid = bx * 256 + tid, nthr = gridDim.x * 256;
  const int w = tid >> 6, l = tid & 63, lo = l & 15, hi = l >> 4;

  // ---------------- setup: reorder+cast weights, fuse biases, init h ----------------
  {
    const int nv0 = NGATE * (KA / 8);
    for (int i = gtid; i < nv0; i += nthr) {
      int r = i / (KA / 8), k = (i - r * (KA / 8)) * 8;
      int orig = (r & 3) * NHID + (r >> 2);
      const float* s = (k < NFEAT) ? a.Wih0 + orig * NFEAT + k
                                   : a.Whh0 + (size_t)orig * NHID + (k - NFEAT);
      unsigned short t8[8];
      #pragma unroll
      for (int j = 0; j < 8; j++) t8[j] = f2bf(s[j]);
      *(short8*)(a.W0 + (size_t)r * KA + k) = *(short8*)t8;
    }
    const int nv1 = NGATE * (KB / 8);
    for (int i = gtid; i < nv1; i += nthr) {
      int r = i / (KB / 8), k = (i - r * (KB / 8)) * 8;
      int orig = (r & 3) * NHID + (r >> 2);
      const float* s = (k < NHID) ? a.Wih1 + (size_t)orig * NHID + k
                                  : a.Whh1 + (size_t)orig * NHID + (k - NHID);
      unsigned short t8[8];
      #pragma unroll
      for (int j = 0; j < 8; j++) t8[j] = f2bf(s[j]);
      *(short8*)(a.W1 + (size_t)r * KB + k) = *(short8*)t8;
    }
    for (int r = gtid; r < NGATE; r += nthr) {
      int orig = (r & 3) * NHID + (r >> 2);
      a.b0f[r] = a.bih0[orig] + a.bhh0[orig];
      a.b1f[r] = a.bih1[orig] + a.bhh1[orig];
    }
    for (int i = gtid; i < NBATCH * NHID; i += nthr) {
      a.h0b[NBATCH * NHID + i] = f2bf(a.h00[i]);
      a.h1b[NBATCH * NHID + i] = f2bf(a.h01[i]);
    }
  }
  cg::this_grid().sync();

  // role: blocks (bx&127)<64 -> layer0 GEMM, else layer1. (bx, bx+128) share nt => same XCD.
  const bool g0 = (bx & 127) < 64;
  const int nt = bx & 63, mt = bx >> 7;
  float creg[8];
  {
    const float* csrc = g0 ? a.c00 : a.c01;
    int jq = nt * 16 + w * 4 + hi;
    #pragma unroll
    for (int mf = 0; mf < 8; mf++)
      creg[mf] = csrc[(size_t)(mt * 128 + mf * 16 + lo) * NHID + jq];
  }

  // ---------------- 129 pipelined phases: layer0 step p  ||  layer1 step p-1 ----------------
  for (int p = 0; p <= NSTEP; p++) {
    int rp = (p + 1) & 1, wpar = p & 1;
    if (g0) { if (p < NSTEP) gemm_layer(a, true,  p,     rp, wpar, mt, nt, w, lo, hi, creg); }
    else    { if (p >= 1)    gemm_layer(a, false, p - 1, rp, wpar, mt, nt, w, lo, hi, creg); }
    cg::this_grid().sync();
  }

  // ---------------- final GEMM: out[i][o] = outs_flat[i,:] . Wout[o,:] + bout ----------------
  {
    int fnt = bx & 3, kc = bx >> 2;          // 4 o-tiles x 64 k-chunks
    f32x4 acc[4][2];
    #pragma unroll
    for (int i = 0; i < 4; i++) { acc[i][0] = (f32x4)(0.f); acc[i][1] = (f32x4)(0.f); }
    const int kbase = kc * 2048;
    for (int kk = 0; kk < 64; kk++) {
      short8 wf0 = ld8f(a.Wout + (size_t)(fnt*32 +  0 + lo) * KOUT + kbase + kk*32 + hi*8);
      short8 wf1 = ld8f(a.Wout + (size_t)(fnt*32 + 16 + lo) * KOUT + kbase + kk*32 + hi*8);
      #pragma unroll
      for (int mf = 0; mf < 4; mf++) {
        const unsigned short* ip = a.outs + (size_t)((w*4 + mf)*16 + lo) * KOUT + kbase + kk*32 + hi*8;
        short8 af = ld8(ip);
        acc[mf][0] = __builtin_amdgcn_mfma_f32_16x16x32_bf16(wf0, af, acc[mf][0], 0, 0, 0);
        acc[mf][1] = __builtin_amdgcn_mfma_f32_16x16x32_bf16(wf1, af, acc[mf][1], 0, 0, 0);
      }
    }
    #pragma unroll
    for (int mf = 0; mf < 4; mf++)
      #pragma unroll
      for (int nf = 0; nf < 2; nf++)
        #pragma unroll
        for (int r = 0; r < 4; r++) {
          int o_loc = nf*16 + 4*hi + r;
          int i = (w*4 + mf)*16 + lo;
          a.partial[(size_t)(kc*4 + fnt) * 8192 + o_loc * 256 + i] = acc[mf][nf][r];
        }
  }
  cg::this_grid().sync();

  for (int idx = gtid; idx < NBATCH * NOUT; idx += nthr) {
    int i = idx >> 7, o = idx & 127;
    float s = a.bout[o];
    #pragma unroll 4
    for (int kc2 = 0; kc2 < 64; kc2++)
      s += a.partial[(size_t)(kc2*4 + (o >> 5)) * 8192 + (o & 31) * 256 + i];
    a.out[idx] = s;
  }
}

extern "C" void kernel_launch(void* const* d_in, const int* in_sizes, int n_in,
                              void* d_out, int out_size, void* d_ws, size_t ws_size,
                              hipStream_t stream)
{
  (void)in_sizes; (void)n_in; (void)out_size; (void)ws_size;
  Params a;
  a.batch = (const float*)d_in[0];  a.Wih0 = (const float*)d_in[1];
  a.Whh0  = (const float*)d_in[2];  a.bih0 = (const float*)d_in[3];
  a.bhh0  = (const float*)d_in[4];  a.Wih1 = (const float*)d_in[5];
  a.Whh1  = (const float*)d_in[6];  a.bih1 = (const float*)d_in[7];
  a.bhh1  = (const float*)d_in[8];  a.h00  = (const float*)d_in[9];
  a.c00   = (const float*)d_in[10]; a.h01  = (const float*)d_in[11];
  a.c01   = (const float*)d_in[12]; a.Wout = (const float*)d_in[13];
  a.bout  = (const float*)d_in[14];
  a.out   = (float*)d_out;

  char* ws = (char*)d_ws;
  size_t off = 0;
  auto carve = [&](size_t bytes) { char* p = ws + off; off += (bytes + 255) & ~(size_t)255; return p; };
  a.W0      = (unsigned short*)carve((size_t)NGATE * KA * 2);
  a.W1      = (unsigned short*)carve((size_t)NGATE * KB * 2);
  a.h0b     = (unsigned short*)carve((size_t)2 * NBATCH * NHID * 2);
  a.h1b     = (unsigned short*)carve((size_t)2 * NBATCH * NHID * 2);
  a.outs    = (unsigned short*)carve((size_t)NSTEP * NBATCH * NHID * 2);
  a.b0f     = (float*)carve((size_t)NGATE * 4);
  a.b1f     = (float*)carve((size_t)NGATE * 4);
  a.partial = (float*)carve((size_t)256 * 8192 * 4);

  void* kargs[] = { &a };
  hipLaunchCooperativeKernel((void*)lstm_all, dim3(256), dim3(256), kargs, 0, stream);
}

// Round 2
// 10394.860 us; speedup vs baseline: 1.6918x; 1.6918x over previous
//
#include <hip/hip_runtime.h>
#include <hip/hip_cooperative_groups.h>

namespace cg = cooperative_groups;

typedef __attribute__((ext_vector_type(8))) short short8;
typedef __attribute__((ext_vector_type(4))) float f32x4;

#define NBATCH 256
#define NSTEP  128
#define NFEAT  128
#define NHID   1024
#define KA     1152
#define KB     2048
#define NOUT   128
#define KOUT   131072

// LDS layout (bytes)
#define W1_OFF 0
#define W1_BYTES (16 * KB * 2)           // 65536
#define W0_OFF (W1_OFF + W1_BYTES)
#define W0_BYTES (16 * KA * 2)           // 36864
#define HS0_OFF (W0_OFF + W0_BYTES)      // 102400
#define HS1_OFF (HS0_OFF + 2048)
#define SMEM_BYTES (HS1_OFF + 2048)      // 106496

__device__ __forceinline__ unsigned short f2bf(float f){
  unsigned u = __float_as_uint(f);
  u += 0x7fffu + ((u >> 16) & 1u);
  return (unsigned short)(u >> 16);
}
__device__ __forceinline__ float sigf(float x){
  x = fminf(fmaxf(x, -30.f), 30.f);
  return 1.f / (1.f + __expf(-x));
}
__device__ __forceinline__ float tanhf_(float x){
  x = fminf(fmaxf(x, -15.f), 15.f);
  float e = __expf(2.f * x);
  return (e - 1.f) / (e + 1.f);
}

struct Params {
  const float *batch,*Wih0,*Whh0,*bih0,*bhh0,*Wih1,*Whh1,*bih1,*bhh1,*h00,*c00,*h01,*c01,*Wout,*bout;
  float *out;
  unsigned short *h0b,*h1b,*outs,*xbf;
  float *partial;
};

__device__ __forceinline__ short8 ld8(const unsigned short* p){
  return *(const short8*)p;
}
__device__ __forceinline__ short8 ld8f(const float* p){
  f32x4 a = *(const f32x4*)p;
  f32x4 b = *(const f32x4*)(p + 4);
  short8 r;
  r[0]=(short)f2bf(a[0]); r[1]=(short)f2bf(a[1]); r[2]=(short)f2bf(a[2]); r[3]=(short)f2bf(a[3]);
  r[4]=(short)f2bf(b[0]); r[5]=(short)f2bf(b[1]); r[6]=(short)f2bf(b[2]); r[7]=(short)f2bf(b[3]);
  return r;
}

__global__ void __launch_bounds__(512) lstm_all(Params a)
{
  extern __shared__ char smem[];
  const int bx = blockIdx.x, tid = threadIdx.x;
  const int gtid = bx * 512 + tid, nthr = gridDim.x * 512;
  const int w = tid >> 6, l = tid & 63, lo = l & 15, hi = l >> 4;

  // ---------------- setup ----------------
  // Stage this block's 16 reordered gate-rows of W1 and W0 into LDS (bf16, swizzled).
  for (int item = tid; item < 16 * 256; item += 512) {
    int lr = item >> 8, k = (item & 255) * 8;
    int r = 16 * bx + lr, orig = (r & 3) * NHID + (r >> 2);
    const float* src = (k < NHID) ? a.Wih1 + (size_t)orig * NHID + k
                                  : a.Whh1 + (size_t)orig * NHID + (k - NHID);
    int off = (lr * KB + k) * 2;
    off ^= (lr & 7) << 4;
    *(short8*)(smem + W1_OFF + off) = ld8f(src);
  }
  for (int item = tid; item < 16 * 144; item += 512) {
    int lr = item / 144, k = (item % 144) * 8;
    int r = 16 * bx + lr, orig = (r & 3) * NHID + (r >> 2);
    const float* src = (k < NFEAT) ? a.Wih0 + (size_t)orig * NFEAT + k
                                   : a.Whh0 + (size_t)orig * NHID + (k - NFEAT);
    int off = (lr * KA + k) * 2;
    off ^= (lr & 7) << 4;
    *(short8*)(smem + W0_OFF + off) = ld8f(src);
  }
  // h-state init into buffer 1; x pre-cast to bf16.
  for (int i = gtid; i < NBATCH * NHID; i += nthr) {
    a.h0b[NBATCH * NHID + i] = f2bf(a.h00[i]);
    a.h1b[NBATCH * NHID + i] = f2bf(a.h01[i]);
  }
  for (int i = gtid; i < NSTEP * NBATCH * NFEAT / 8; i += nthr)
    *(short8*)(a.xbf + (size_t)i * 8) = ld8f(a.batch + (size_t)i * 8);

  // per-lane persistent state: unit j = 4*bx + hi, batch rows m = w*32 + mf*16 + lo
  const int j = 4 * bx + hi;
  float b0r[4], b1r[4];
  #pragma unroll
  for (int q = 0; q < 4; q++) {
    b0r[q] = a.bih0[q * NHID + j] + a.bhh0[q * NHID + j];
    b1r[q] = a.bih1[q * NHID + j] + a.bhh1[q * NHID + j];
  }
  float c0r[2], c1r[2];
  #pragma unroll
  for (int mf = 0; mf < 2; mf++) {
    int m = w * 32 + mf * 16 + lo;
    c0r[mf] = a.c00[(size_t)m * NHID + j];
    c1r[mf] = a.c01[(size_t)m * NHID + j];
  }
  __syncthreads();
  cg::this_grid().sync();

  unsigned short* hs0 = (unsigned short*)(smem + HS0_OFF);
  unsigned short* hs1 = (unsigned short*)(smem + HS1_OFF);
  const int m0 = w * 32 + lo, m1 = m0 + 16;

  // ---------------- 129 pipelined phases: layer0 step p || layer1 step p-1 ----------------
  for (int p = 0; p <= NSTEP; p++) {
    const int wpar = p & 1, rp = wpar ^ 1;
    const unsigned short* h0prev = a.h0b + (size_t)rp   * NBATCH * NHID;
    const unsigned short* h1prev = a.h1b + (size_t)wpar * NBATCH * NHID;

    if (p < NSTEP) {
      f32x4 acc0 = {0.f,0.f,0.f,0.f}, acc1 = {0.f,0.f,0.f,0.f};
      const unsigned short* xp = a.xbf + (size_t)p * NBATCH * NFEAT;
      #pragma unroll
      for (int kc = 0; kc < 4; kc++) {
        int off = ((lo * KA + kc * 32 + hi * 8) * 2) ^ ((lo & 7) << 4);
        short8 wf = *(const short8*)(smem + W0_OFF + off);
        short8 a0 = ld8(xp + (size_t)m0 * NFEAT + kc * 32 + hi * 8);
        short8 a1 = ld8(xp + (size_t)m1 * NFEAT + kc * 32 + hi * 8);
        acc0 = __builtin_amdgcn_mfma_f32_16x16x32_bf16(wf, a0, acc0, 0, 0, 0);
        acc1 = __builtin_amdgcn_mfma_f32_16x16x32_bf16(wf, a1, acc1, 0, 0, 0);
      }
      #pragma unroll 8
      for (int kc = 4; kc < 36; kc++) {
        int off = ((lo * KA + kc * 32 + hi * 8) * 2) ^ ((lo & 7) << 4);
        short8 wf = *(const short8*)(smem + W0_OFF + off);
        int k = kc * 32 - NFEAT + hi * 8;
        short8 a0 = ld8(h0prev + (size_t)m0 * NHID + k);
        short8 a1 = ld8(h0prev + (size_t)m1 * NHID + k);
        acc0 = __builtin_amdgcn_mfma_f32_16x16x32_bf16(wf, a0, acc0, 0, 0, 0);
        acc1 = __builtin_amdgcn_mfma_f32_16x16x32_bf16(wf, a1, acc1, 0, 0, 0);
      }
      {
        float cn0 = sigf(acc0[1] + b0r[1]) * c0r[0] + sigf(acc0[0] + b0r[0]) * tanhf_(acc0[2] + b0r[2]);
        c0r[0] = cn0;
        hs0[(w * 32 + lo) * 4 + hi] = f2bf(sigf(acc0[3] + b0r[3]) * tanhf_(cn0));
        float cn1 = sigf(acc1[1] + b0r[1]) * c0r[1] + sigf(acc1[0] + b0r[0]) * tanhf_(acc1[2] + b0r[2]);
        c0r[1] = cn1;
        hs0[(w * 32 + 16 + lo) * 4 + hi] = f2bf(sigf(acc1[3] + b0r[3]) * tanhf_(cn1));
      }
    }
    __syncthreads();
    if (p < NSTEP && tid < NBATCH) {
      unsigned long long v = *(const unsigned long long*)(hs0 + tid * 4);
      *(unsigned long long*)(a.h0b + (size_t)wpar * NBATCH * NHID + (size_t)tid * NHID + 4 * bx) = v;
    }

    if (p >= 1) {
      f32x4 acc0 = {0.f,0.f,0.f,0.f}, acc1 = {0.f,0.f,0.f,0.f};
      #pragma unroll 8
      for (int kc = 0; kc < 32; kc++) {
        int off = ((lo * KB + kc * 32 + hi * 8) * 2) ^ ((lo & 7) << 4);
        short8 wf = *(const short8*)(smem + W1_OFF + off);
        int k = kc * 32 + hi * 8;
        short8 a0 = ld8(h0prev + (size_t)m0 * NHID + k);
        short8 a1 = ld8(h0prev + (size_t)m1 * NHID + k);
        acc0 = __builtin_amdgcn_mfma_f32_16x16x32_bf16(wf, a0, acc0, 0, 0, 0);
        acc1 = __builtin_amdgcn_mfma_f32_16x16x32_bf16(wf, a1, acc1, 0, 0, 0);
      }
      #pragma unroll 8
      for (int kc = 32; kc < 64; kc++) {
        int off = ((lo * KB + kc * 32 + hi * 8) * 2) ^ ((lo & 7) << 4);
        short8 wf = *(const short8*)(smem + W1_OFF + off);
        int k = (kc - 32) * 32 + hi * 8;
        short8 a0 = ld8(h1prev + (size_t)m0 * NHID + k);
        short8 a1 = ld8(h1prev + (size_t)m1 * NHID + k);
        acc0 = __builtin_amdgcn_mfma_f32_16x16x32_bf16(wf, a0, acc0, 0, 0, 0);
        acc1 = __builtin_amdgcn_mfma_f32_16x16x32_bf16(wf, a1, acc1, 0, 0, 0);
      }
      {
        float cn0 = sigf(acc0[1] + b1r[1]) * c1r[0] + sigf(acc0[0] + b1r[0]) * tanhf_(acc0[2] + b1r[2]);
        c1r[0] = cn0;
        hs1[(w * 32 + lo) * 4 + hi] = f2bf(sigf(acc0[3] + b1r[3]) * tanhf_(cn0));
        float cn1 = sigf(acc1[1] + b1r[1]) * c1r[1] + sigf(acc1[0] + b1r[0]) * tanhf_(acc1[2] + b1r[2]);
        c1r[1] = cn1;
        hs1[(w * 32 + 16 + lo) * 4 + hi] = f2bf(sigf(acc1[3] + b1r[3]) * tanhf_(cn1));
      }
    }
    __syncthreads();
    if (p >= 1 && tid < NBATCH) {
      unsigned long long v = *(const unsigned long long*)(hs1 + tid * 4);
      *(unsigned long long*)(a.h1b + (size_t)rp * NBATCH * NHID + (size_t)tid * NHID + 4 * bx) = v;
      *(unsigned long long*)(a.outs + (size_t)(p - 1) * NBATCH * NHID + (size_t)tid * NHID + 4 * bx) = v;
    }
    cg::this_grid().sync();
  }

  // ---------------- final GEMM: out[i][o] = outs_flat[i,:] . Wout[o,:] + bout ----------------
  {
    int fnt = bx & 3, kc = bx >> 2;      // 4 o-tiles x 64 k-chunks of 2048
    f32x4 facc[2][2];
    #pragma unroll
    for (int i = 0; i < 2; i++) { facc[i][0] = (f32x4)(0.f); facc[i][1] = (f32x4)(0.f); }
    const int kbase = kc * 2048;
    for (int kk = 0; kk < 64; kk++) {
      short8 wf0 = ld8f(a.Wout + (size_t)(fnt * 32 +  0 + lo) * KOUT + kbase + kk * 32 + hi * 8);
      short8 wf1 = ld8f(a.Wout + (size_t)(fnt * 32 + 16 + lo) * KOUT + kbase + kk * 32 + hi * 8);
      #pragma unroll
      for (int mf = 0; mf < 2; mf++) {
        const unsigned short* ip = a.outs + (size_t)((w * 2 + mf) * 16 + lo) * KOUT + kbase + kk * 32 + hi * 8;
        short8 af = ld8(ip);
        facc[mf][0] = __builtin_amdgcn_mfma_f32_16x16x32_bf16(wf0, af, facc[mf][0], 0, 0, 0);
        facc[mf][1] = __builtin_amdgcn_mfma_f32_16x16x32_bf16(wf1, af, facc[mf][1], 0, 0, 0);
      }
    }
    #pragma unroll
    for (int mf = 0; mf < 2; mf++)
      #pragma unroll
      for (int nf = 0; nf < 2; nf++)
        #pragma unroll
        for (int r = 0; r < 4; r++) {
          int o_loc = nf * 16 + 4 * hi + r;
          int i = (w * 2 + mf) * 16 + lo;
          a.partial[(size_t)(kc * 4 + fnt) * 8192 + o_loc * 256 + i] = facc[mf][nf][r];
        }
  }
  cg::this_grid().sync();

  for (int idx = gtid; idx < NBATCH * NOUT; idx += nthr) {
    int i = idx >> 7, o = idx & 127;
    float s = a.bout[o];
    #pragma unroll 4
    for (int kc2 = 0; kc2 < 64; kc2++)
      s += a.partial[(size_t)(kc2 * 4 + (o >> 5)) * 8192 + (o & 31) * 256 + i];
    a.out[idx] = s;
  }
}

extern "C" void kernel_launch(void* const* d_in, const int* in_sizes, int n_in,
                              void* d_out, int out_size, void* d_ws, size_t ws_size,
                              hipStream_t stream)
{
  (void)in_sizes; (void)n_in; (void)out_size; (void)ws_size;
  Params a;
  a.batch = (const float*)d_in[0];  a.Wih0 = (const float*)d_in[1];
  a.Whh0  = (const float*)d_in[2];  a.bih0 = (const float*)d_in[3];
  a.bhh0  = (const float*)d_in[4];  a.Wih1 = (const float*)d_in[5];
  a.Whh1  = (const float*)d_in[6];  a.bih1 = (const float*)d_in[7];
  a.bhh1  = (const float*)d_in[8];  a.h00  = (const float*)d_in[9];
  a.c00   = (const float*)d_in[10]; a.h01  = (const float*)d_in[11];
  a.c01   = (const float*)d_in[12]; a.Wout = (const float*)d_in[13];
  a.bout  = (const float*)d_in[14];
  a.out   = (float*)d_out;

  char* ws = (char*)d_ws;
  size_t off = 0;
  auto carve = [&](size_t bytes) { char* p = ws + off; off += (bytes + 255) & ~(size_t)255; return p; };
  a.h0b     = (unsigned short*)carve((size_t)2 * NBATCH * NHID * 2);
  a.h1b     = (unsigned short*)carve((size_t)2 * NBATCH * NHID * 2);
  a.outs    = (unsigned short*)carve((size_t)NSTEP * NBATCH * NHID * 2);
  a.xbf     = (unsigned short*)carve((size_t)NSTEP * NBATCH * NFEAT * 2);
  a.partial = (float*)carve((size_t)256 * 8192 * 4);

  static int attr_done = 0;
  hipFuncSetAttribute((const void*)lstm_all, hipFuncAttributeMaxDynamicSharedMemorySize, SMEM_BYTES);
  (void)attr_done;

  void* kargs[] = { &a };
  hipLaunchCooperativeKernel((void*)lstm_all, dim3(256), dim3(512), kargs, SMEM_BYTES, stream);
}

// Round 3
// 8675.447 us; speedup vs baseline: 2.0272x; 1.1982x over previous
//
#include <hip/hip_runtime.h>
#include <hip/hip_cooperative_groups.h>

namespace cg = cooperative_groups;

typedef __attribute__((ext_vector_type(8))) short short8;
typedef __attribute__((ext_vector_type(4))) float f32x4;

#define NBATCH 256
#define NSTEP  128
#define NFEAT  128
#define NHID   1024
#define KA     1152
#define KB     2048
#define NOUT   128
#define KOUT   131072

// LDS layout (bytes)
#define W1_OFF 0
#define W1_BYTES (16 * KB * 2)           // 65536
#define W0_OFF (W1_OFF + W1_BYTES)
#define W0_BYTES (16 * KA * 2)           // 36864
#define HS0_OFF (W0_OFF + W0_BYTES)      // 102400
#define HS1_OFF (HS0_OFF + 2048)
#define SMEM_BYTES (HS1_OFF + 2048)      // 106496

__device__ __forceinline__ unsigned short f2bf(float f){
  unsigned u = __float_as_uint(f);
  u += 0x7fffu + ((u >> 16) & 1u);
  return (unsigned short)(u >> 16);
}
__device__ __forceinline__ float sigf(float x){
  x = fminf(fmaxf(x, -30.f), 30.f);
  return 1.f / (1.f + __expf(-x));
}
__device__ __forceinline__ float tanhf_(float x){
  x = fminf(fmaxf(x, -15.f), 15.f);
  float e = __expf(2.f * x);
  return (e - 1.f) / (e + 1.f);
}

struct Params {
  const float *batch,*Wih0,*Whh0,*bih0,*bhh0,*Wih1,*Whh1,*bih1,*bhh1,*h00,*c00,*h01,*c01,*Wout,*bout;
  float *out;
  unsigned short *h0b,*h1b,*outs,*xbf;
  float *partial;
};

__device__ __forceinline__ short8 ld8(const unsigned short* p){
  return *(const short8*)p;
}
__device__ __forceinline__ short8 ld8f(const float* p){
  f32x4 a = *(const f32x4*)p;
  f32x4 b = *(const f32x4*)(p + 4);
  short8 r;
  r[0]=(short)f2bf(a[0]); r[1]=(short)f2bf(a[1]); r[2]=(short)f2bf(a[2]); r[3]=(short)f2bf(a[3]);
  r[4]=(short)f2bf(b[0]); r[5]=(short)f2bf(b[1]); r[6]=(short)f2bf(b[2]); r[7]=(short)f2bf(b[3]);
  return r;
}

__global__ void __launch_bounds__(512, 2) lstm_all(Params a)
{
  extern __shared__ char smem[];
  const int bx = blockIdx.x, tid = threadIdx.x;
  const int gtid = bx * 512 + tid, nthr = gridDim.x * 512;
  const int w = tid >> 6, l = tid & 63, lo = l & 15, hi = l >> 4;

  // ---------------- setup ----------------
  // Stage this block's 16 reordered gate-rows of W1 and W0 into LDS (bf16, swizzled).
  for (int item = tid; item < 16 * 256; item += 512) {
    int lr = item >> 8, k = (item & 255) * 8;
    int r = 16 * bx + lr, orig = (r & 3) * NHID + (r >> 2);
    const float* src = (k < NHID) ? a.Wih1 + (size_t)orig * NHID + k
                                  : a.Whh1 + (size_t)orig * NHID + (k - NHID);
    int off = (lr * KB + k) * 2;
    off ^= (lr & 7) << 4;
    *(short8*)(smem + W1_OFF + off) = ld8f(src);
  }
  for (int item = tid; item < 16 * 144; item += 512) {
    int lr = item / 144, k = (item % 144) * 8;
    int r = 16 * bx + lr, orig = (r & 3) * NHID + (r >> 2);
    const float* src = (k < NFEAT) ? a.Wih0 + (size_t)orig * NFEAT + k
                                   : a.Whh0 + (size_t)orig * NHID + (k - NFEAT);
    int off = (lr * KA + k) * 2;
    off ^= (lr & 7) << 4;
    *(short8*)(smem + W0_OFF + off) = ld8f(src);
  }
  // h-state init into buffer 1; x pre-cast to bf16.
  for (int i = gtid; i < NBATCH * NHID; i += nthr) {
    a.h0b[NBATCH * NHID + i] = f2bf(a.h00[i]);
    a.h1b[NBATCH * NHID + i] = f2bf(a.h01[i]);
  }
  for (int i = gtid; i < NSTEP * NBATCH * NFEAT / 8; i += nthr)
    *(short8*)(a.xbf + (size_t)i * 8) = ld8f(a.batch + (size_t)i * 8);

  // per-lane persistent state: unit j = 4*bx + hi, batch rows m = w*32 + {lo, 16+lo}
  const int j = 4 * bx + hi;
  float b0r[4], b1r[4];
  #pragma unroll
  for (int q = 0; q < 4; q++) {
    b0r[q] = a.bih0[q * NHID + j] + a.bhh0[q * NHID + j];
    b1r[q] = a.bih1[q * NHID + j] + a.bhh1[q * NHID + j];
  }
  float c0r[2], c1r[2];
  #pragma unroll
  for (int mf = 0; mf < 2; mf++) {
    int m = w * 32 + mf * 16 + lo;
    c0r[mf] = a.c00[(size_t)m * NHID + j];
    c1r[mf] = a.c01[(size_t)m * NHID + j];
  }
  __syncthreads();
  cg::this_grid().sync();

  unsigned short* hs0 = (unsigned short*)(smem + HS0_OFF);
  unsigned short* hs1 = (unsigned short*)(smem + HS1_OFF);
  const int m0 = w * 32 + lo, m1 = m0 + 16;

  // ---------------- 129 pipelined phases: layer0 step p || layer1 step p-1 ----------------
  // Fused: both layers' reads of h0prev happen in ONE pass (seg B).
  for (int p = 0; p <= NSTEP; p++) {
    const int wpar = p & 1, rp = wpar ^ 1;
    const unsigned short* h0prev = a.h0b + (size_t)rp   * NBATCH * NHID;
    const unsigned short* h1prev = a.h1b + (size_t)wpar * NBATCH * NHID;
    const int t0 = (p < NSTEP) ? p : (NSTEP - 1);  // clamp so p==128 reads in-bounds (discarded)

    f32x4 l0a0 = {0.f,0.f,0.f,0.f}, l0a1 = {0.f,0.f,0.f,0.f};
    f32x4 l1a0 = {0.f,0.f,0.f,0.f}, l1a1 = {0.f,0.f,0.f,0.f};

    // seg A: x_t  (k = 0..127 of layer0)
    {
      const unsigned short* xp = a.xbf + (size_t)t0 * NBATCH * NFEAT;
      #pragma unroll
      for (int kc = 0; kc < 4; kc++) {
        int off = ((lo * KA + kc * 32 + hi * 8) * 2) ^ ((lo & 7) << 4);
        short8 wf = *(const short8*)(smem + W0_OFF + off);
        short8 a0 = ld8(xp + (size_t)m0 * NFEAT + kc * 32 + hi * 8);
        short8 a1 = ld8(xp + (size_t)m1 * NFEAT + kc * 32 + hi * 8);
        l0a0 = __builtin_amdgcn_mfma_f32_16x16x32_bf16(wf, a0, l0a0, 0, 0, 0);
        l0a1 = __builtin_amdgcn_mfma_f32_16x16x32_bf16(wf, a1, l0a1, 0, 0, 0);
      }
    }
    // seg B: h0prev feeds BOTH layer0 (k=128..1151) and layer1 (k=0..1023)
    #pragma unroll 8
    for (int kc = 0; kc < 32; kc++) {
      int k = kc * 32 + hi * 8;
      short8 a0 = ld8(h0prev + (size_t)m0 * NHID + k);
      short8 a1 = ld8(h0prev + (size_t)m1 * NHID + k);
      int offA = ((lo * KA + NFEAT + k) * 2) ^ ((lo & 7) << 4);
      int offB = ((lo * KB + k) * 2) ^ ((lo & 7) << 4);
      short8 w0f = *(const short8*)(smem + W0_OFF + offA);
      short8 w1f = *(const short8*)(smem + W1_OFF + offB);
      l0a0 = __builtin_amdgcn_mfma_f32_16x16x32_bf16(w0f, a0, l0a0, 0, 0, 0);
      l0a1 = __builtin_amdgcn_mfma_f32_16x16x32_bf16(w0f, a1, l0a1, 0, 0, 0);
      l1a0 = __builtin_amdgcn_mfma_f32_16x16x32_bf16(w1f, a0, l1a0, 0, 0, 0);
      l1a1 = __builtin_amdgcn_mfma_f32_16x16x32_bf16(w1f, a1, l1a1, 0, 0, 0);
    }
    // seg C: h1prev (k = 1024..2047 of layer1)
    #pragma unroll 8
    for (int kc = 0; kc < 32; kc++) {
      int k = kc * 32 + hi * 8;
      int off = ((lo * KB + NHID + k) * 2) ^ ((lo & 7) << 4);
      short8 wf = *(const short8*)(smem + W1_OFF + off);
      short8 a0 = ld8(h1prev + (size_t)m0 * NHID + k);
      short8 a1 = ld8(h1prev + (size_t)m1 * NHID + k);
      l1a0 = __builtin_amdgcn_mfma_f32_16x16x32_bf16(wf, a0, l1a0, 0, 0, 0);
      l1a1 = __builtin_amdgcn_mfma_f32_16x16x32_bf16(wf, a1, l1a1, 0, 0, 0);
    }

    // epilogues (lane-local cell update; gates i,f,g,o in acc[0..3])
    if (p < NSTEP) {
      float cn0 = sigf(l0a0[1] + b0r[1]) * c0r[0] + sigf(l0a0[0] + b0r[0]) * tanhf_(l0a0[2] + b0r[2]);
      c0r[0] = cn0;
      hs0[(w * 32 + lo) * 4 + hi] = f2bf(sigf(l0a0[3] + b0r[3]) * tanhf_(cn0));
      float cn1 = sigf(l0a1[1] + b0r[1]) * c0r[1] + sigf(l0a1[0] + b0r[0]) * tanhf_(l0a1[2] + b0r[2]);
      c0r[1] = cn1;
      hs0[(w * 32 + 16 + lo) * 4 + hi] = f2bf(sigf(l0a1[3] + b0r[3]) * tanhf_(cn1));
    }
    if (p >= 1) {
      float cn0 = sigf(l1a0[1] + b1r[1]) * c1r[0] + sigf(l1a0[0] + b1r[0]) * tanhf_(l1a0[2] + b1r[2]);
      c1r[0] = cn0;
      hs1[(w * 32 + lo) * 4 + hi] = f2bf(sigf(l1a0[3] + b1r[3]) * tanhf_(cn0));
      float cn1 = sigf(l1a1[1] + b1r[1]) * c1r[1] + sigf(l1a1[0] + b1r[0]) * tanhf_(l1a1[2] + b1r[2]);
      c1r[1] = cn1;
      hs1[(w * 32 + 16 + lo) * 4 + hi] = f2bf(sigf(l1a1[3] + b1r[3]) * tanhf_(cn1));
    }
    __syncthreads();
    if (tid < NBATCH) {
      if (p < NSTEP) {
        unsigned long long v = *(const unsigned long long*)(hs0 + tid * 4);
        *(unsigned long long*)(a.h0b + (size_t)wpar * NBATCH * NHID + (size_t)tid * NHID + 4 * bx) = v;
      }
      if (p >= 1) {
        unsigned long long v = *(const unsigned long long*)(hs1 + tid * 4);
        *(unsigned long long*)(a.h1b + (size_t)rp * NBATCH * NHID + (size_t)tid * NHID + 4 * bx) = v;
        *(unsigned long long*)(a.outs + (size_t)(p - 1) * NBATCH * NHID + (size_t)tid * NHID + 4 * bx) = v;
      }
    }
    cg::this_grid().sync();
  }

  // ---------------- final GEMM: out[i][o] = outs_flat[i,:] . Wout[o,:] + bout ----------------
  {
    int fnt = bx & 3, kc = bx >> 2;      // 4 o-tiles x 64 k-chunks of 2048
    f32x4 facc[2][2];
    #pragma unroll
    for (int i = 0; i < 2; i++) { facc[i][0] = (f32x4)(0.f); facc[i][1] = (f32x4)(0.f); }
    const int kbase = kc * 2048;
    for (int kk = 0; kk < 64; kk++) {
      short8 wf0 = ld8f(a.Wout + (size_t)(fnt * 32 +  0 + lo) * KOUT + kbase + kk * 32 + hi * 8);
      short8 wf1 = ld8f(a.Wout + (size_t)(fnt * 32 + 16 + lo) * KOUT + kbase + kk * 32 + hi * 8);
      #pragma unroll
      for (int mf = 0; mf < 2; mf++) {
        const unsigned short* ip = a.outs + (size_t)((w * 2 + mf) * 16 + lo) * KOUT + kbase + kk * 32 + hi * 8;
        short8 af = ld8(ip);
        facc[mf][0] = __builtin_amdgcn_mfma_f32_16x16x32_bf16(wf0, af, facc[mf][0], 0, 0, 0);
        facc[mf][1] = __builtin_amdgcn_mfma_f32_16x16x32_bf16(wf1, af, facc[mf][1], 0, 0, 0);
      }
    }
    #pragma unroll
    for (int mf = 0; mf < 2; mf++)
      #pragma unroll
      for (int nf = 0; nf < 2; nf++)
        #pragma unroll
        for (int r = 0; r < 4; r++) {
          int o_loc = nf * 16 + 4 * hi + r;
          int i = (w * 2 + mf) * 16 + lo;
          a.partial[(size_t)(kc * 4 + fnt) * 8192 + o_loc * 256 + i] = facc[mf][nf][r];
        }
  }
  cg::this_grid().sync();

  for (int idx = gtid; idx < NBATCH * NOUT; idx += nthr) {
    int i = idx >> 7, o = idx & 127;
    float s = a.bout[o];
    #pragma unroll 4
    for (int kc2 = 0; kc2 < 64; kc2++)
      s += a.partial[(size_t)(kc2 * 4 + (o >> 5)) * 8192 + (o & 31) * 256 + i];
    a.out[idx] = s;
  }
}

extern "C" void kernel_launch(void* const* d_in, const int* in_sizes, int n_in,
                              void* d_out, int out_size, void* d_ws, size_t ws_size,
                              hipStream_t stream)
{
  (void)in_sizes; (void)n_in; (void)out_size; (void)ws_size;
  Params a;
  a.batch = (const float*)d_in[0];  a.Wih0 = (const float*)d_in[1];
  a.Whh0  = (const float*)d_in[2];  a.bih0 = (const float*)d_in[3];
  a.bhh0  = (const float*)d_in[4];  a.Wih1 = (const float*)d_in[5];
  a.Whh1  = (const float*)d_in[6];  a.bih1 = (const float*)d_in[7];
  a.bhh1  = (const float*)d_in[8];  a.h00  = (const float*)d_in[9];
  a.c00   = (const float*)d_in[10]; a.h01  = (const float*)d_in[11];
  a.c01   = (const float*)d_in[12]; a.Wout = (const float*)d_in[13];
  a.bout  = (const float*)d_in[14];
  a.out   = (float*)d_out;

  char* ws = (char*)d_ws;
  size_t off = 0;
  auto carve = [&](size_t bytes) { char* p = ws + off; off += (bytes + 255) & ~(size_t)255; return p; };
  a.h0b     = (unsigned short*)carve((size_t)2 * NBATCH * NHID * 2);
  a.h1b     = (unsigned short*)carve((size_t)2 * NBATCH * NHID * 2);
  a.outs    = (unsigned short*)carve((size_t)NSTEP * NBATCH * NHID * 2);
  a.xbf     = (unsigned short*)carve((size_t)NSTEP * NBATCH * NFEAT * 2);
  a.partial = (float*)carve((size_t)256 * 8192 * 4);

  hipFuncSetAttribute((const void*)lstm_all, hipFuncAttributeMaxDynamicSharedMemorySize, SMEM_BYTES);

  void* kargs[] = { &a };
  hipLaunchCooperativeKernel((void*)lstm_all, dim3(256), dim3(512), kargs, SMEM_BYTES, stream);
}

// Round 4
// 8592.355 us; speedup vs baseline: 2.0468x; 1.0097x over previous
//
#include <hip/hip_runtime.h>
#include <hip/hip_cooperative_groups.h>

namespace cg = cooperative_groups;

typedef __attribute__((ext_vector_type(8))) short short8;
typedef __attribute__((ext_vector_type(4))) float f32x4;

#define NBATCH 256
#define NSTEP  128
#define NFEAT  128
#define NHID   1024
#define KA     1152
#define KB     2048
#define NOUT   128
#define KOUT   131072

// LDS layout (bytes)
#define W1_OFF 0
#define W1_BYTES (16 * KB * 2)           // 65536
#define W0_OFF (W1_OFF + W1_BYTES)
#define W0_BYTES (16 * KA * 2)           // 36864
#define HS0_OFF (W0_OFF + W0_BYTES)      // 102400
#define HS1_OFF (HS0_OFF + 2048)
#define SMEM_BYTES (HS1_OFF + 2048)      // 106496

__device__ __forceinline__ unsigned short f2bf(float f){
  unsigned u = __float_as_uint(f);
  u += 0x7fffu + ((u >> 16) & 1u);
  return (unsigned short)(u >> 16);
}
__device__ __forceinline__ float sigf(float x){
  x = fminf(fmaxf(x, -30.f), 30.f);
  return 1.f / (1.f + __expf(-x));
}
__device__ __forceinline__ float tanhf_(float x){
  x = fminf(fmaxf(x, -15.f), 15.f);
  float e = __expf(2.f * x);
  return (e - 1.f) / (e + 1.f);
}

struct Params {
  const float *batch,*Wih0,*Whh0,*bih0,*bhh0,*Wih1,*Whh1,*bih1,*bhh1,*h00,*c00,*h01,*c01,*Wout,*bout;
  float *out;
  unsigned short *h0b,*h1b,*outs,*xbf;
  float *partial;
};

__device__ __forceinline__ short8 ld8(const unsigned short* p){
  return *(const short8*)p;
}
__device__ __forceinline__ short8 ld8f(const float* p){
  f32x4 a = *(const f32x4*)p;
  f32x4 b = *(const f32x4*)(p + 4);
  short8 r;
  r[0]=(short)f2bf(a[0]); r[1]=(short)f2bf(a[1]); r[2]=(short)f2bf(a[2]); r[3]=(short)f2bf(a[3]);
  r[4]=(short)f2bf(b[0]); r[5]=(short)f2bf(b[1]); r[6]=(short)f2bf(b[2]); r[7]=(short)f2bf(b[3]);
  return r;
}

// ---- software-pipeline helpers (all statically indexed, fully unrolled) ----
__device__ __forceinline__ void load_chunk(short8 (&buf)[16], const unsigned short* ha,
                                           const unsigned short* hb, int kbase) {
  #pragma unroll
  for (int q = 0; q < 8; q++) {
    buf[2*q]   = ld8(ha + kbase + q*32);
    buf[2*q+1] = ld8(hb + kbase + q*32);
  }
}
__device__ __forceinline__ void mfma_h0(const short8 (&buf)[16], const char* smem,
                                        int c0, int lo, int klane,
                                        f32x4& l0a0, f32x4& l0a1, f32x4& l1a0, f32x4& l1a1) {
  #pragma unroll
  for (int q = 0; q < 8; q++) {
    int kk = c0*256 + q*32 + klane;
    int offA = ((lo * KA + NFEAT + kk) * 2) ^ ((lo & 7) << 4);
    int offB = ((lo * KB + kk) * 2) ^ ((lo & 7) << 4);
    short8 w0f = *(const short8*)(smem + W0_OFF + offA);
    short8 w1f = *(const short8*)(smem + W1_OFF + offB);
    l0a0 = __builtin_amdgcn_mfma_f32_16x16x32_bf16(w0f, buf[2*q],   l0a0, 0, 0, 0);
    l0a1 = __builtin_amdgcn_mfma_f32_16x16x32_bf16(w0f, buf[2*q+1], l0a1, 0, 0, 0);
    l1a0 = __builtin_amdgcn_mfma_f32_16x16x32_bf16(w1f, buf[2*q],   l1a0, 0, 0, 0);
    l1a1 = __builtin_amdgcn_mfma_f32_16x16x32_bf16(w1f, buf[2*q+1], l1a1, 0, 0, 0);
  }
}
__device__ __forceinline__ void mfma_h1(const short8 (&buf)[16], const char* smem,
                                        int c0, int lo, int klane,
                                        f32x4& l1a0, f32x4& l1a1) {
  #pragma unroll
  for (int q = 0; q < 8; q++) {
    int kk = c0*256 + q*32 + klane;
    int off = ((lo * KB + NHID + kk) * 2) ^ ((lo & 7) << 4);
    short8 wf = *(const short8*)(smem + W1_OFF + off);
    l1a0 = __builtin_amdgcn_mfma_f32_16x16x32_bf16(wf, buf[2*q],   l1a0, 0, 0, 0);
    l1a1 = __builtin_amdgcn_mfma_f32_16x16x32_bf16(wf, buf[2*q+1], l1a1, 0, 0, 0);
  }
}

__global__ void __launch_bounds__(512, 2) lstm_all(Params a)
{
  extern __shared__ char smem[];
  const int bx = blockIdx.x, tid = threadIdx.x;
  const int gtid = bx * 512 + tid, nthr = gridDim.x * 512;
  const int w = tid >> 6, l = tid & 63, lo = l & 15, hi = l >> 4;
  const int klane = hi * 8;

  // ---------------- setup ----------------
  for (int item = tid; item < 16 * 256; item += 512) {
    int lr = item >> 8, k = (item & 255) * 8;
    int r = 16 * bx + lr, orig = (r & 3) * NHID + (r >> 2);
    const float* src = (k < NHID) ? a.Wih1 + (size_t)orig * NHID + k
                                  : a.Whh1 + (size_t)orig * NHID + (k - NHID);
    int off = (lr * KB + k) * 2;
    off ^= (lr & 7) << 4;
    *(short8*)(smem + W1_OFF + off) = ld8f(src);
  }
  for (int item = tid; item < 16 * 144; item += 512) {
    int lr = item / 144, k = (item % 144) * 8;
    int r = 16 * bx + lr, orig = (r & 3) * NHID + (r >> 2);
    const float* src = (k < NFEAT) ? a.Wih0 + (size_t)orig * NFEAT + k
                                   : a.Whh0 + (size_t)orig * NHID + (k - NFEAT);
    int off = (lr * KA + k) * 2;
    off ^= (lr & 7) << 4;
    *(short8*)(smem + W0_OFF + off) = ld8f(src);
  }
  for (int i = gtid; i < NBATCH * NHID; i += nthr) {
    a.h0b[NBATCH * NHID + i] = f2bf(a.h00[i]);
    a.h1b[NBATCH * NHID + i] = f2bf(a.h01[i]);
  }
  for (int i = gtid; i < NSTEP * NBATCH * NFEAT / 8; i += nthr)
    *(short8*)(a.xbf + (size_t)i * 8) = ld8f(a.batch + (size_t)i * 8);

  // per-lane persistent state: unit j = 4*bx + hi, batch rows m = w*32 + {lo, 16+lo}
  const int j = 4 * bx + hi;
  float b0r[4], b1r[4];
  #pragma unroll
  for (int q = 0; q < 4; q++) {
    b0r[q] = a.bih0[q * NHID + j] + a.bhh0[q * NHID + j];
    b1r[q] = a.bih1[q * NHID + j] + a.bhh1[q * NHID + j];
  }
  float c0r[2], c1r[2];
  #pragma unroll
  for (int mf = 0; mf < 2; mf++) {
    int m = w * 32 + mf * 16 + lo;
    c0r[mf] = a.c00[(size_t)m * NHID + j];
    c1r[mf] = a.c01[(size_t)m * NHID + j];
  }
  __syncthreads();
  cg::this_grid().sync();

  unsigned short* hs0 = (unsigned short*)(smem + HS0_OFF);
  unsigned short* hs1 = (unsigned short*)(smem + HS1_OFF);
  const int m0 = w * 32 + lo, m1 = m0 + 16;

  // ---------------- 129 pipelined phases: layer0 step p || layer1 step p-1 ----------------
  for (int p = 0; p <= NSTEP; p++) {
    const int wpar = p & 1, rp = wpar ^ 1;
    const unsigned short* h0prev = a.h0b + (size_t)rp   * NBATCH * NHID;
    const unsigned short* h1prev = a.h1b + (size_t)wpar * NBATCH * NHID;
    const int t0 = (p < NSTEP) ? p : (NSTEP - 1);

    const unsigned short* h0A = h0prev + (size_t)m0 * NHID + klane;
    const unsigned short* h0B = h0prev + (size_t)m1 * NHID + klane;
    const unsigned short* h1A = h1prev + (size_t)m0 * NHID + klane;
    const unsigned short* h1B = h1prev + (size_t)m1 * NHID + klane;

    f32x4 l0a0 = {0.f,0.f,0.f,0.f}, l0a1 = {0.f,0.f,0.f,0.f};
    f32x4 l1a0 = {0.f,0.f,0.f,0.f}, l1a1 = {0.f,0.f,0.f,0.f};

    // issue x loads + first two h0 chunks, then compute behind them (3-buffer ring, 2 ahead)
    short8 xb[8];
    {
      const unsigned short* xp = a.xbf + (size_t)t0 * NBATCH * NFEAT;
      #pragma unroll
      for (int kc = 0; kc < 4; kc++) {
        xb[2*kc]   = ld8(xp + (size_t)m0 * NFEAT + kc*32 + klane);
        xb[2*kc+1] = ld8(xp + (size_t)m1 * NFEAT + kc*32 + klane);
      }
    }
    short8 b0[16], b1[16], b2[16];
    load_chunk(b0, h0A, h0B, 0*256);
    load_chunk(b1, h0A, h0B, 1*256);
    // seg A: x_t (k = 0..127 of layer0)
    #pragma unroll
    for (int kc = 0; kc < 4; kc++) {
      int off = ((lo * KA + kc * 32 + klane) * 2) ^ ((lo & 7) << 4);
      short8 wf = *(const short8*)(smem + W0_OFF + off);
      l0a0 = __builtin_amdgcn_mfma_f32_16x16x32_bf16(wf, xb[2*kc],   l0a0, 0, 0, 0);
      l0a1 = __builtin_amdgcn_mfma_f32_16x16x32_bf16(wf, xb[2*kc+1], l0a1, 0, 0, 0);
    }
    load_chunk(b2, h0A, h0B, 2*256);  mfma_h0(b0, smem, 0, lo, klane, l0a0, l0a1, l1a0, l1a1);
    load_chunk(b0, h0A, h0B, 3*256);  mfma_h0(b1, smem, 1, lo, klane, l0a0, l0a1, l1a0, l1a1);
    load_chunk(b1, h1A, h1B, 0*256);  mfma_h0(b2, smem, 2, lo, klane, l0a0, l0a1, l1a0, l1a1);
    load_chunk(b2, h1A, h1B, 1*256);  mfma_h0(b0, smem, 3, lo, klane, l0a0, l0a1, l1a0, l1a1);
    load_chunk(b0, h1A, h1B, 2*256);  mfma_h1(b1, smem, 0, lo, klane, l1a0, l1a1);
    load_chunk(b1, h1A, h1B, 3*256);  mfma_h1(b2, smem, 1, lo, klane, l1a0, l1a1);
    mfma_h1(b0, smem, 2, lo, klane, l1a0, l1a1);
    mfma_h1(b1, smem, 3, lo, klane, l1a0, l1a1);

    // epilogues (lane-local cell update; gates i,f,g,o in acc[0..3])
    if (p < NSTEP) {
      float cn0 = sigf(l0a0[1] + b0r[1]) * c0r[0] + sigf(l0a0[0] + b0r[0]) * tanhf_(l0a0[2] + b0r[2]);
      c0r[0] = cn0;
      hs0[(w * 32 + lo) * 4 + hi] = f2bf(sigf(l0a0[3] + b0r[3]) * tanhf_(cn0));
      float cn1 = sigf(l0a1[1] + b0r[1]) * c0r[1] + sigf(l0a1[0] + b0r[0]) * tanhf_(l0a1[2] + b0r[2]);
      c0r[1] = cn1;
      hs0[(w * 32 + 16 + lo) * 4 + hi] = f2bf(sigf(l0a1[3] + b0r[3]) * tanhf_(cn1));
    }
    if (p >= 1) {
      float cn0 = sigf(l1a0[1] + b1r[1]) * c1r[0] + sigf(l1a0[0] + b1r[0]) * tanhf_(l1a0[2] + b1r[2]);
      c1r[0] = cn0;
      hs1[(w * 32 + lo) * 4 + hi] = f2bf(sigf(l1a0[3] + b1r[3]) * tanhf_(cn0));
      float cn1 = sigf(l1a1[1] + b1r[1]) * c1r[1] + sigf(l1a1[0] + b1r[0]) * tanhf_(l1a1[2] + b1r[2]);
      c1r[1] = cn1;
      hs1[(w * 32 + 16 + lo) * 4 + hi] = f2bf(sigf(l1a1[3] + b1r[3]) * tanhf_(cn1));
    }
    __syncthreads();
    if (tid < NBATCH) {
      if (p < NSTEP) {
        unsigned long long v = *(const unsigned long long*)(hs0 + tid * 4);
        *(unsigned long long*)(a.h0b + (size_t)wpar * NBATCH * NHID + (size_t)tid * NHID + 4 * bx) = v;
      }
      if (p >= 1) {
        unsigned long long v = *(const unsigned long long*)(hs1 + tid * 4);
        *(unsigned long long*)(a.h1b + (size_t)rp * NBATCH * NHID + (size_t)tid * NHID + 4 * bx) = v;
        *(unsigned long long*)(a.outs + (size_t)(p - 1) * NBATCH * NHID + (size_t)tid * NHID + 4 * bx) = v;
      }
    }
    cg::this_grid().sync();
  }

  // ---------------- final GEMM: out[i][o] = outs_flat[i,:] . Wout[o,:] + bout ----------------
  {
    int fnt = bx & 3, kc = bx >> 2;      // 4 o-tiles x 64 k-chunks of 2048
    f32x4 facc[2][2];
    #pragma unroll
    for (int i = 0; i < 2; i++) { facc[i][0] = (f32x4)(0.f); facc[i][1] = (f32x4)(0.f); }
    const int kbase = kc * 2048;
    #pragma unroll 2
    for (int kk = 0; kk < 64; kk++) {
      short8 wf0 = ld8f(a.Wout + (size_t)(fnt * 32 +  0 + lo) * KOUT + kbase + kk * 32 + hi * 8);
      short8 wf1 = ld8f(a.Wout + (size_t)(fnt * 32 + 16 + lo) * KOUT + kbase + kk * 32 + hi * 8);
      #pragma unroll
      for (int mf = 0; mf < 2; mf++) {
        const unsigned short* ip = a.outs + (size_t)((w * 2 + mf) * 16 + lo) * KOUT + kbase + kk * 32 + hi * 8;
        short8 af = ld8(ip);
        facc[mf][0] = __builtin_amdgcn_mfma_f32_16x16x32_bf16(wf0, af, facc[mf][0], 0, 0, 0);
        facc[mf][1] = __builtin_amdgcn_mfma_f32_16x16x32_bf16(wf1, af, facc[mf][1], 0, 0, 0);
      }
    }
    #pragma unroll
    for (int mf = 0; mf < 2; mf++)
      #pragma unroll
      for (int nf = 0; nf < 2; nf++)
        #pragma unroll
        for (int r = 0; r < 4; r++) {
          int o_loc = nf * 16 + 4 * hi + r;
          int i = (w * 2 + mf) * 16 + lo;
          a.partial[(size_t)(kc * 4 + fnt) * 8192 + o_loc * 256 + i] = facc[mf][nf][r];
        }
  }
  cg::this_grid().sync();

  for (int idx = gtid; idx < NBATCH * NOUT; idx += nthr) {
    int i = idx >> 7, o = idx & 127;
    float s = a.bout[o];
    #pragma unroll 4
    for (int kc2 = 0; kc2 < 64; kc2++)
      s += a.partial[(size_t)(kc2 * 4 + (o >> 5)) * 8192 + (o & 31) * 256 + i];
    a.out[idx] = s;
  }
}

extern "C" void kernel_launch(void* const* d_in, const int* in_sizes, int n_in,
                              void* d_out, int out_size, void* d_ws, size_t ws_size,
                              hipStream_t stream)
{
  (void)in_sizes; (void)n_in; (void)out_size; (void)ws_size;
  Params a;
  a.batch = (const float*)d_in[0];  a.Wih0 = (const float*)d_in[1];
  a.Whh0  = (const float*)d_in[2];  a.bih0 = (const float*)d_in[3];
  a.bhh0  = (const float*)d_in[4];  a.Wih1 = (const float*)d_in[5];
  a.Whh1  = (const float*)d_in[6];  a.bih1 = (const float*)d_in[7];
  a.bhh1  = (const float*)d_in[8];  a.h00  = (const float*)d_in[9];
  a.c00   = (const float*)d_in[10]; a.h01  = (const float*)d_in[11];
  a.c01   = (const float*)d_in[12]; a.Wout = (const float*)d_in[13];
  a.bout  = (const float*)d_in[14];
  a.out   = (float*)d_out;

  char* ws = (char*)d_ws;
  size_t off = 0;
  auto carve = [&](size_t bytes) { char* p = ws + off; off += (bytes + 255) & ~(size_t)255; return p; };
  a.h0b     = (unsigned short*)carve((size_t)2 * NBATCH * NHID * 2);
  a.h1b     = (unsigned short*)carve((size_t)2 * NBATCH * NHID * 2);
  a.outs    = (unsigned short*)carve((size_t)NSTEP * NBATCH * NHID * 2);
  a.xbf     = (unsigned short*)carve((size_t)NSTEP * NBATCH * NFEAT * 2);
  a.partial = (float*)carve((size_t)256 * 8192 * 4);

  hipFuncSetAttribute((const void*)lstm_all, hipFuncAttributeMaxDynamicSharedMemorySize, SMEM_BYTES);

  void* kargs[] = { &a };
  hipLaunchCooperativeKernel((void*)lstm_all, dim3(256), dim3(512), kargs, SMEM_BYTES, stream);
}